// Round 8
// baseline (138.895 us; speedup 1.0000x reference)
//
#include <hip/hip_runtime.h>
#include <hip/hip_fp16.h>
#include <math.h>

// Problem geometry (fixed by setup_inputs)
#define NT    32
#define NA    64
#define NB    64
#define NGEO  128
#define NELEM (NT * NA * NB * NGEO)   // 16777216 = 2^24
#define GR    64
#define NQ    (GR * GR * GR)          // 262144 cells
#define QBYTES ((size_t)NQ * 16)      // 4 MiB packed fp16-cube table

// clang ext-vector types (HIP_vector_type is rejected by the nontemporal
// builtins). Same layout / codegen as float4 & uint4.
typedef float        vf4 __attribute__((ext_vector_type(4)));
typedef unsigned int vu4 __attribute__((ext_vector_type(4)));

// ---------------------------------------------------------------------------
// Pre-pass: pack each cell's full 2x2x2 corner cube as 8 x fp16 in ONE 16B
// record -> the main kernel does a single aligned dwordx4 gather per point.
// fp16 value error <= 2^-11 relative (grid |v|~10 -> net error <=0.005 ->
// <=0.5% emission error, 4x under the 2% threshold).
// rec = { v000,v001 | v010,v011 | v100,v101 | v110,v111 } packed lo/hi.
__global__ __launch_bounds__(256) void build_cube(
    const float* __restrict__ g, vu4* __restrict__ q)
{
    int idx = blockIdx.x * 256 + threadIdx.x;          // 0 .. NQ-1
    int z = idx & 63, y = (idx >> 6) & 63, x = idx >> 12;
    int zc = min(z + 1, 63), yc = min(y + 1, 63), xc = min(x + 1, 63);
    const float* g0 = g + x  * 4096;
    const float* g1 = g + xc * 4096;
    int b00 = y * 64 + z,  b01 = y * 64 + zc;
    int b10 = yc * 64 + z, b11 = yc * 64 + zc;

    auto pack2 = [](float a, float b) -> unsigned {
        unsigned lo = __half_as_ushort(__float2half(a));
        unsigned hi = __half_as_ushort(__float2half(b));
        return lo | (hi << 16);
    };
    vu4 v;
    v.x = pack2(g0[b00], g0[b01]);
    v.y = pack2(g0[b10], g0[b11]);
    v.z = pack2(g1[b00], g1[b01]);
    v.w = pack2(g1[b10], g1[b11]);
    q[idx] = v;
}

// ---------------------------------------------------------------------------
// Accuracy contract (absmax threshold = 2% of max output):
//  * MASK decisions (t_rot>=0, 2<=r<=10, |z|<=4) bit-match the numpy f32
//    reference -> __f*_rn intrinsics (no fp-contract) + rounded sqrtf.
//    Verified absmax==0.0 in R1/R2/R4/R5/R6/R7.
//  * Value path (rotation, weights, fp16 table, sigmoid) is continuous;
//    worst-case ~0.5% relative emission error, 4x under threshold.
struct Prep {
    int   bidx;
    bool  alive;
    float wx0, wx1, wy0, wy1, wz0, wz1;
};

__device__ __forceinline__ Prep prep_point(
    float x, float y, float z, float Om, float tg, float tM, float tinj)
{
    Prep p;
    float t_rot = __fsub_rn(__fsub_rn(tM, tg), tinj);
    float r2 = __fadd_rn(__fadd_rn(__fmul_rn(x, x), __fmul_rn(y, y)),
                         __fmul_rn(z, z));
    float r = sqrtf(r2);

    p.alive = (t_rot >= 0.0f) & (r >= 2.0f) & (r <= 10.0f) &
              (fabsf(z) <= 4.0f);

    // warp-back rotation about z (hardware sin/cos take revolutions)
    float theta = -Om * t_rot;
    float rev = theta * 0.15915494309189535f;
    rev = rev - floorf(rev);
    float s = __builtin_amdgcn_sinf(rev);
    float c = __builtin_amdgcn_cosf(rev);
    float xw = x * c - y * s;
    float yw = x * s + y * c;

    // grid index space: (v + 10) / 20 * 63, clamped into [0, 63)
    float fx = (xw + 10.0f) * 3.15f;
    float fy = (yw + 10.0f) * 3.15f;
    float fz = (z  + 10.0f) * 3.15f;
    fx = fminf(fmaxf(fx, 0.0f), 62.999996f);
    fy = fminf(fmaxf(fy, 0.0f), 62.999996f);
    fz = fminf(fmaxf(fz, 0.0f), 62.999996f);

    int ix0 = (int)fx, iy0 = (int)fy, iz0 = (int)fz;
    p.wx1 = fx - (float)ix0; p.wy1 = fy - (float)iy0; p.wz1 = fz - (float)iz0;
    p.wx0 = 1.0f - p.wx1;    p.wy0 = 1.0f - p.wy1;    p.wz0 = 1.0f - p.wz1;

    int bidx = ix0 * 4096 + iy0 * 64 + iz0;
    p.bidx = p.alive ? bidx : 0;   // dead lanes: broadcast line, no branch
    return p;
}

__device__ __forceinline__ float2 cvt2(unsigned u)
{
    __half2 h = *reinterpret_cast<__half2*>(&u);
    return __half22float2(h);      // 2x v_cvt_f32_f16
}

__device__ __forceinline__ float finish_point(const Prep& p, vu4 cbe)
{
    float2 q00 = cvt2(cbe.x);      // v000, v001
    float2 q01 = cvt2(cbe.y);      // v010, v011
    float2 q10 = cvt2(cbe.z);      // v100, v101
    float2 q11 = cvt2(cbe.w);      // v110, v111

    float c00 = q00.x * p.wz0 + q00.y * p.wz1;
    float c01 = q01.x * p.wz0 + q01.y * p.wz1;
    float c10 = q10.x * p.wz0 + q10.y * p.wz1;
    float c11 = q11.x * p.wz0 + q11.y * p.wz1;
    float c0  = c00 * p.wy0 + c01 * p.wy1;
    float c1  = c10 * p.wy0 + c11 * p.wy1;
    float net = c0 * p.wx0 + c1 * p.wx1;

    float E = __expf(10.0f - net);                 // sigmoid(net - 10)
    float sig = __builtin_amdgcn_rcpf(1.0f + E);
    return p.alive ? sig : 0.0f;
}

#define NTLOAD(ptr)  __builtin_nontemporal_load((const vf4*)(ptr))

// R8: 8 points/thread (two groups of 4). All 10 nt stream loads issue up
// front -> 2x the per-wave memory-level parallelism of R6, half the waves.
// nt on streams proven +5us in R7 A/B (protects the 4MB table in L2).
__global__ __launch_bounds__(256) void grid_predictor8(
    const float* __restrict__ t_frames,
    const float* __restrict__ coords,
    const float* __restrict__ Omega,
    const float* __restrict__ t_geos,
    const float* __restrict__ t_inj,
    const float* __restrict__ t_start,
    const vu4*  __restrict__ q,
    float* __restrict__ out)
{
    int i = (blockIdx.x * 256 + threadIdx.x) * 8;

    // 2048 elems per block, 2^19 per t-plane -> t uniform per block
    int t = blockIdx.x >> 8;
    float tM   = __fsub_rn(t_frames[t], t_start[0]);
    float tinj = t_inj[0];

    // issue ALL stream loads up front (10 x dwordx4 nt, in flight together)
    vf4 xa = NTLOAD(coords + i);
    vf4 xb = NTLOAD(coords + i + 4);
    vf4 ya = NTLOAD(coords + NELEM + i);
    vf4 yb = NTLOAD(coords + NELEM + i + 4);
    vf4 za = NTLOAD(coords + 2 * NELEM + i);
    vf4 zb = NTLOAD(coords + 2 * NELEM + i + 4);
    vf4 oa = NTLOAD(Omega + i);
    vf4 ob = NTLOAD(Omega + i + 4);
    vf4 ga = NTLOAD(t_geos + i);
    vf4 gb = NTLOAD(t_geos + i + 4);

    // ---- group A ----
    Prep p0 = prep_point(xa.x, ya.x, za.x, oa.x, ga.x, tM, tinj);
    Prep p1 = prep_point(xa.y, ya.y, za.y, oa.y, ga.y, tM, tinj);
    Prep p2 = prep_point(xa.z, ya.z, za.z, oa.z, ga.z, tM, tinj);
    Prep p3 = prep_point(xa.w, ya.w, za.w, oa.w, ga.w, tM, tinj);
    vu4 c0 = q[p0.bidx];
    vu4 c1 = q[p1.bidx];
    vu4 c2 = q[p2.bidx];
    vu4 c3 = q[p3.bidx];

    // ---- group B prep + gathers (issue while A's gathers are in flight) ----
    Prep p4 = prep_point(xb.x, yb.x, zb.x, ob.x, gb.x, tM, tinj);
    Prep p5 = prep_point(xb.y, yb.y, zb.y, ob.y, gb.y, tM, tinj);
    Prep p6 = prep_point(xb.z, yb.z, zb.z, ob.z, gb.z, tM, tinj);
    Prep p7 = prep_point(xb.w, yb.w, zb.w, ob.w, gb.w, tM, tinj);
    vu4 c4 = q[p4.bidx];
    vu4 c5 = q[p5.bidx];
    vu4 c6 = q[p6.bidx];
    vu4 c7 = q[p7.bidx];

    // ---- finish + store ----
    vf4 ra, rb;
    ra.x = finish_point(p0, c0);
    ra.y = finish_point(p1, c1);
    ra.z = finish_point(p2, c2);
    ra.w = finish_point(p3, c3);
    __builtin_nontemporal_store(ra, (vf4*)(out + i));
    rb.x = finish_point(p4, c4);
    rb.y = finish_point(p5, c5);
    rb.z = finish_point(p6, c6);
    rb.w = finish_point(p7, c7);
    __builtin_nontemporal_store(rb, (vf4*)(out + i + 4));
}

// Fallback (no workspace): R6's 4-pt direct-grid kernel, f32 gathers.
__global__ __launch_bounds__(256) void grid_predictor4_raw(
    const float* __restrict__ t_frames,
    const float* __restrict__ coords,
    const float* __restrict__ Omega,
    const float* __restrict__ t_geos,
    const float* __restrict__ t_inj,
    const float* __restrict__ t_start,
    const float* __restrict__ g,
    float* __restrict__ out)
{
    int i = (blockIdx.x * 256 + threadIdx.x) * 4;
    int t = blockIdx.x >> 9;
    float tM   = __fsub_rn(t_frames[t], t_start[0]);
    float tinj = t_inj[0];

    vf4 x4 = NTLOAD(coords + i);
    vf4 y4 = NTLOAD(coords + NELEM + i);
    vf4 z4 = NTLOAD(coords + 2 * NELEM + i);
    vf4 o4 = NTLOAD(Omega + i);
    vf4 g4 = NTLOAD(t_geos + i);

    Prep pp[4] = {
        prep_point(x4.x, y4.x, z4.x, o4.x, g4.x, tM, tinj),
        prep_point(x4.y, y4.y, z4.y, o4.y, g4.y, tM, tinj),
        prep_point(x4.z, y4.z, z4.z, o4.z, g4.z, tM, tinj),
        prep_point(x4.w, y4.w, z4.w, o4.w, g4.w, tM, tinj)};

    vf4 r;
    #pragma unroll
    for (int k = 0; k < 4; ++k) {
        const Prep& p = pp[k];
        const float* h = g + p.bidx;
        float c00 = h[0]    * p.wz0 + h[1]    * p.wz1;
        float c01 = h[64]   * p.wz0 + h[65]   * p.wz1;
        float c10 = h[4096] * p.wz0 + h[4097] * p.wz1;
        float c11 = h[4160] * p.wz0 + h[4161] * p.wz1;
        float c0  = c00 * p.wy0 + c01 * p.wy1;
        float c1  = c10 * p.wy0 + c11 * p.wy1;
        float net = c0 * p.wx0 + c1 * p.wx1;
        float E = __expf(10.0f - net);
        float v = __builtin_amdgcn_rcpf(1.0f + E);
        v = p.alive ? v : 0.0f;
        if (k == 0) r.x = v; else if (k == 1) r.y = v;
        else if (k == 2) r.z = v; else r.w = v;
    }
    __builtin_nontemporal_store(r, (vf4*)(out + i));
}

extern "C" void kernel_launch(void* const* d_in, const int* in_sizes, int n_in,
                              void* d_out, int out_size, void* d_ws, size_t ws_size,
                              hipStream_t stream) {
    const float* t_frames = (const float*)d_in[0];
    const float* coords   = (const float*)d_in[1];
    const float* Omega    = (const float*)d_in[2];
    const float* t_geos   = (const float*)d_in[3];
    const float* t_inj    = (const float*)d_in[4];
    const float* t_start  = (const float*)d_in[5];
    const float* grid     = (const float*)d_in[6];
    float* out = (float*)d_out;

    if (ws_size >= QBYTES) {
        vu4* q = (vu4*)d_ws;
        build_cube<<<NQ / 256, 256, 0, stream>>>(grid, q);
        grid_predictor8<<<NELEM / 8 / 256, 256, 0, stream>>>(
            t_frames, coords, Omega, t_geos, t_inj, t_start, q, out);
    } else {
        grid_predictor4_raw<<<NELEM / 4 / 256, 256, 0, stream>>>(
            t_frames, coords, Omega, t_geos, t_inj, t_start, grid, out);
    }
}

// Round 9
// 95.631 us; speedup vs baseline: 1.4524x; 1.4524x over previous
//
#include <hip/hip_runtime.h>
#include <hip/hip_fp16.h>
#include <math.h>

// Problem geometry (fixed by setup_inputs)
#define NT    32
#define NA    64
#define NB    64
#define NGEO  128
#define NELEM (NT * NA * NB * NGEO)   // 16777216 = 2^24
#define GR    64
#define NQ    (GR * GR * GR)          // 262144 cells
#define QBYTES ((size_t)NQ * 16)      // 4 MiB packed fp16-cube table

// clang ext-vector types (HIP_vector_type is rejected by the nontemporal
// builtins). Same layout / codegen as float4 & uint4.
typedef float        vf4 __attribute__((ext_vector_type(4)));
typedef unsigned int vu4 __attribute__((ext_vector_type(4)));

// ---------------------------------------------------------------------------
// Pre-pass: pack each cell's full 2x2x2 corner cube as 8 x fp16 in ONE 16B
// record -> the main kernel does a single aligned dwordx4 gather per point.
// fp16 value error <= 2^-11 relative -> <=0.5% emission error, 4x under the
// 2% threshold. rec = { v000,v001 | v010,v011 | v100,v101 | v110,v111 }.
__global__ __launch_bounds__(256) void build_cube(
    const float* __restrict__ g, vu4* __restrict__ q)
{
    int idx = blockIdx.x * 256 + threadIdx.x;          // 0 .. NQ-1
    int z = idx & 63, y = (idx >> 6) & 63, x = idx >> 12;
    int zc = min(z + 1, 63), yc = min(y + 1, 63), xc = min(x + 1, 63);
    const float* g0 = g + x  * 4096;
    const float* g1 = g + xc * 4096;
    int b00 = y * 64 + z,  b01 = y * 64 + zc;
    int b10 = yc * 64 + z, b11 = yc * 64 + zc;

    auto pack2 = [](float a, float b) -> unsigned {
        unsigned lo = __half_as_ushort(__float2half(a));
        unsigned hi = __half_as_ushort(__float2half(b));
        return lo | (hi << 16);
    };
    vu4 v;
    v.x = pack2(g0[b00], g0[b01]);
    v.y = pack2(g0[b10], g0[b11]);
    v.z = pack2(g1[b00], g1[b01]);
    v.w = pack2(g1[b10], g1[b11]);
    q[idx] = v;
}

// ---------------------------------------------------------------------------
// Accuracy contract (absmax threshold = 2% of max output):
//  * MASK decisions (t_rot>=0, 2<=r<=10, |z|<=4) bit-match the numpy f32
//    reference -> __f*_rn intrinsics (no fp-contract) + rounded sqrtf.
//    Verified absmax==0.0 in R1..R8.
//  * Value path (rotation, weights, fp16 table, sigmoid) is continuous;
//    worst-case ~0.5% relative emission error, 4x under threshold.
struct Prep {
    int   bidx;
    bool  alive;
    float wx0, wx1, wy0, wy1, wz0, wz1;
};

__device__ __forceinline__ Prep prep_point(
    float x, float y, float z, float Om, float tg, float tM, float tinj)
{
    Prep p;
    float t_rot = __fsub_rn(__fsub_rn(tM, tg), tinj);
    float r2 = __fadd_rn(__fadd_rn(__fmul_rn(x, x), __fmul_rn(y, y)),
                         __fmul_rn(z, z));
    float r = sqrtf(r2);

    p.alive = (t_rot >= 0.0f) & (r >= 2.0f) & (r <= 10.0f) &
              (fabsf(z) <= 4.0f);

    // warp-back rotation about z (hardware sin/cos take revolutions)
    float theta = -Om * t_rot;
    float rev = theta * 0.15915494309189535f;
    rev = rev - floorf(rev);
    float s = __builtin_amdgcn_sinf(rev);
    float c = __builtin_amdgcn_cosf(rev);
    float xw = x * c - y * s;
    float yw = x * s + y * c;

    // grid index space: (v + 10) / 20 * 63, clamped into [0, 63)
    float fx = (xw + 10.0f) * 3.15f;
    float fy = (yw + 10.0f) * 3.15f;
    float fz = (z  + 10.0f) * 3.15f;
    fx = fminf(fmaxf(fx, 0.0f), 62.999996f);
    fy = fminf(fmaxf(fy, 0.0f), 62.999996f);
    fz = fminf(fmaxf(fz, 0.0f), 62.999996f);

    int ix0 = (int)fx, iy0 = (int)fy, iz0 = (int)fz;
    p.wx1 = fx - (float)ix0; p.wy1 = fy - (float)iy0; p.wz1 = fz - (float)iz0;
    p.wx0 = 1.0f - p.wx1;    p.wy0 = 1.0f - p.wy1;    p.wz0 = 1.0f - p.wz1;

    int bidx = ix0 * 4096 + iy0 * 64 + iz0;
    p.bidx = p.alive ? bidx : 0;   // dead lanes: broadcast line, no branch
    return p;
}

__device__ __forceinline__ float2 cvt2(unsigned u)
{
    __half2 h = *reinterpret_cast<__half2*>(&u);
    return __half22float2(h);      // 2x v_cvt_f32_f16
}

__device__ __forceinline__ float finish_point(const Prep& p, vu4 cbe)
{
    float2 q00 = cvt2(cbe.x);      // v000, v001
    float2 q01 = cvt2(cbe.y);      // v010, v011
    float2 q10 = cvt2(cbe.z);      // v100, v101
    float2 q11 = cvt2(cbe.w);      // v110, v111

    float c00 = q00.x * p.wz0 + q00.y * p.wz1;
    float c01 = q01.x * p.wz0 + q01.y * p.wz1;
    float c10 = q10.x * p.wz0 + q10.y * p.wz1;
    float c11 = q11.x * p.wz0 + q11.y * p.wz1;
    float c0  = c00 * p.wy0 + c01 * p.wy1;
    float c1  = c10 * p.wy0 + c11 * p.wy1;
    float net = c0 * p.wx0 + c1 * p.wx1;

    float E = __expf(10.0f - net);                 // sigmoid(net - 10)
    float sig = __builtin_amdgcn_rcpf(1.0f + E);
    return p.alive ? sig : 0.0f;
}

#define NTLOAD(ptr)  __builtin_nontemporal_load((const vf4*)(ptr))

// R9: 8 points/thread via TWO DISTANT WINDOWS (A at ia, B at ia+NELEM/2).
// Every stream instruction is wave-contiguous 16B/lane -> zero line
// amplification (R8's adjacent-8 layout amplified FETCH 1.7x / WRITE 1.9x).
// 10 stream loads + 8 gathers in flight per thread = 2x R6's per-wave MLP.
__global__ __launch_bounds__(256) void grid_predictor8(
    const float* __restrict__ t_frames,
    const float* __restrict__ coords,
    const float* __restrict__ Omega,
    const float* __restrict__ t_geos,
    const float* __restrict__ t_inj,
    const float* __restrict__ t_start,
    const vu4*  __restrict__ q,
    float* __restrict__ out)
{
    int tid = blockIdx.x * 256 + threadIdx.x;
    int ia = tid * 4;                  // window A: [0, NELEM/2)
    int ib = ia + NELEM / 2;           // window B: [NELEM/2, NELEM)

    // block covers 1024 contiguous elems per window; plane = 2^19
    int ta = blockIdx.x >> 9;          // t for window A (0..15)
    float ts0  = t_start[0];
    float tinj = t_inj[0];
    float tMa = __fsub_rn(t_frames[ta], ts0);
    float tMb = __fsub_rn(t_frames[ta + 16], ts0);

    // issue ALL stream loads up front (10 x dwordx4 nt, in flight together)
    vf4 xa = NTLOAD(coords + ia);
    vf4 ya = NTLOAD(coords + NELEM + ia);
    vf4 za = NTLOAD(coords + 2 * NELEM + ia);
    vf4 oa = NTLOAD(Omega + ia);
    vf4 ga = NTLOAD(t_geos + ia);
    vf4 xb = NTLOAD(coords + ib);
    vf4 yb = NTLOAD(coords + NELEM + ib);
    vf4 zb = NTLOAD(coords + 2 * NELEM + ib);
    vf4 ob = NTLOAD(Omega + ib);
    vf4 gb = NTLOAD(t_geos + ib);

    // ---- window A: prep + gathers ----
    Prep p0 = prep_point(xa.x, ya.x, za.x, oa.x, ga.x, tMa, tinj);
    Prep p1 = prep_point(xa.y, ya.y, za.y, oa.y, ga.y, tMa, tinj);
    Prep p2 = prep_point(xa.z, ya.z, za.z, oa.z, ga.z, tMa, tinj);
    Prep p3 = prep_point(xa.w, ya.w, za.w, oa.w, ga.w, tMa, tinj);
    vu4 c0 = q[p0.bidx];
    vu4 c1 = q[p1.bidx];
    vu4 c2 = q[p2.bidx];
    vu4 c3 = q[p3.bidx];

    // ---- window B: prep + gathers (issue while A's gathers fly) ----
    Prep p4 = prep_point(xb.x, yb.x, zb.x, ob.x, gb.x, tMb, tinj);
    Prep p5 = prep_point(xb.y, yb.y, zb.y, ob.y, gb.y, tMb, tinj);
    Prep p6 = prep_point(xb.z, yb.z, zb.z, ob.z, gb.z, tMb, tinj);
    Prep p7 = prep_point(xb.w, yb.w, zb.w, ob.w, gb.w, tMb, tinj);
    vu4 c4 = q[p4.bidx];
    vu4 c5 = q[p5.bidx];
    vu4 c6 = q[p6.bidx];
    vu4 c7 = q[p7.bidx];

    // ---- finish + store (each store wave-contiguous 16B/lane) ----
    vf4 ra;
    ra.x = finish_point(p0, c0);
    ra.y = finish_point(p1, c1);
    ra.z = finish_point(p2, c2);
    ra.w = finish_point(p3, c3);
    __builtin_nontemporal_store(ra, (vf4*)(out + ia));

    vf4 rb;
    rb.x = finish_point(p4, c4);
    rb.y = finish_point(p5, c5);
    rb.z = finish_point(p6, c6);
    rb.w = finish_point(p7, c7);
    __builtin_nontemporal_store(rb, (vf4*)(out + ib));
}

// Fallback (no workspace): 4-pt direct-grid kernel, f32 gathers.
__global__ __launch_bounds__(256) void grid_predictor4_raw(
    const float* __restrict__ t_frames,
    const float* __restrict__ coords,
    const float* __restrict__ Omega,
    const float* __restrict__ t_geos,
    const float* __restrict__ t_inj,
    const float* __restrict__ t_start,
    const float* __restrict__ g,
    float* __restrict__ out)
{
    int i = (blockIdx.x * 256 + threadIdx.x) * 4;
    int t = blockIdx.x >> 9;
    float tM   = __fsub_rn(t_frames[t], t_start[0]);
    float tinj = t_inj[0];

    vf4 x4 = NTLOAD(coords + i);
    vf4 y4 = NTLOAD(coords + NELEM + i);
    vf4 z4 = NTLOAD(coords + 2 * NELEM + i);
    vf4 o4 = NTLOAD(Omega + i);
    vf4 g4 = NTLOAD(t_geos + i);

    Prep pp[4] = {
        prep_point(x4.x, y4.x, z4.x, o4.x, g4.x, tM, tinj),
        prep_point(x4.y, y4.y, z4.y, o4.y, g4.y, tM, tinj),
        prep_point(x4.z, y4.z, z4.z, o4.z, g4.z, tM, tinj),
        prep_point(x4.w, y4.w, z4.w, o4.w, g4.w, tM, tinj)};

    vf4 r;
    #pragma unroll
    for (int k = 0; k < 4; ++k) {
        const Prep& p = pp[k];
        const float* h = g + p.bidx;
        float c00 = h[0]    * p.wz0 + h[1]    * p.wz1;
        float c01 = h[64]   * p.wz0 + h[65]   * p.wz1;
        float c10 = h[4096] * p.wz0 + h[4097] * p.wz1;
        float c11 = h[4160] * p.wz0 + h[4161] * p.wz1;
        float c0  = c00 * p.wy0 + c01 * p.wy1;
        float c1  = c10 * p.wy0 + c11 * p.wy1;
        float net = c0 * p.wx0 + c1 * p.wx1;
        float E = __expf(10.0f - net);
        float v = __builtin_amdgcn_rcpf(1.0f + E);
        v = p.alive ? v : 0.0f;
        if (k == 0) r.x = v; else if (k == 1) r.y = v;
        else if (k == 2) r.z = v; else r.w = v;
    }
    __builtin_nontemporal_store(r, (vf4*)(out + i));
}

extern "C" void kernel_launch(void* const* d_in, const int* in_sizes, int n_in,
                              void* d_out, int out_size, void* d_ws, size_t ws_size,
                              hipStream_t stream) {
    const float* t_frames = (const float*)d_in[0];
    const float* coords   = (const float*)d_in[1];
    const float* Omega    = (const float*)d_in[2];
    const float* t_geos   = (const float*)d_in[3];
    const float* t_inj    = (const float*)d_in[4];
    const float* t_start  = (const float*)d_in[5];
    const float* grid     = (const float*)d_in[6];
    float* out = (float*)d_out;

    if (ws_size >= QBYTES) {
        vu4* q = (vu4*)d_ws;
        build_cube<<<NQ / 256, 256, 0, stream>>>(grid, q);
        grid_predictor8<<<NELEM / 8 / 256, 256, 0, stream>>>(
            t_frames, coords, Omega, t_geos, t_inj, t_start, q, out);
    } else {
        grid_predictor4_raw<<<NELEM / 4 / 256, 256, 0, stream>>>(
            t_frames, coords, Omega, t_geos, t_inj, t_start, grid, out);
    }
}

// Round 10
// 91.659 us; speedup vs baseline: 1.5153x; 1.0433x over previous
//
#include <hip/hip_runtime.h>
#include <hip/hip_fp16.h>
#include <math.h>

// Problem geometry (fixed by setup_inputs)
#define NT    32
#define NA    64
#define NB    64
#define NGEO  128
#define NELEM (NT * NA * NB * NGEO)   // 16777216 = 2^24
#define GR    64
#define NQ    (GR * GR * GR)          // 262144 cells
#define QBYTES ((size_t)NQ * 16)      // 4 MiB packed fp16-cube table

// clang ext-vector types (HIP_vector_type is rejected by the nontemporal
// builtins). Same layout / codegen as float4 & uint4.
typedef float        vf4 __attribute__((ext_vector_type(4)));
typedef unsigned int vu4 __attribute__((ext_vector_type(4)));

// ---------------------------------------------------------------------------
// Pre-pass: pack each cell's full 2x2x2 corner cube as 8 x fp16 in ONE 16B
// record -> the main kernel does a single aligned dwordx4 gather per point
// (was 2 in R4, 8 in R2). fp16 value error <= 2^-11 relative (grid |v|~10
// -> net error <=0.005 -> <=0.5% emission error, 4x under the 2% threshold).
// rec = { v000,v001 | v010,v011 | v100,v101 | v110,v111 } packed lo/hi.
__global__ __launch_bounds__(256) void build_cube(
    const float* __restrict__ g, vu4* __restrict__ q)
{
    int idx = blockIdx.x * 256 + threadIdx.x;          // 0 .. NQ-1
    int z = idx & 63, y = (idx >> 6) & 63, x = idx >> 12;
    int zc = min(z + 1, 63), yc = min(y + 1, 63), xc = min(x + 1, 63);
    const float* g0 = g + x  * 4096;
    const float* g1 = g + xc * 4096;
    int b00 = y * 64 + z,  b01 = y * 64 + zc;
    int b10 = yc * 64 + z, b11 = yc * 64 + zc;

    auto pack2 = [](float a, float b) -> unsigned {
        unsigned lo = __half_as_ushort(__float2half(a));
        unsigned hi = __half_as_ushort(__float2half(b));
        return lo | (hi << 16);
    };
    vu4 v;
    v.x = pack2(g0[b00], g0[b01]);
    v.y = pack2(g0[b10], g0[b11]);
    v.z = pack2(g1[b00], g1[b01]);
    v.w = pack2(g1[b10], g1[b11]);
    q[idx] = v;
}

// ---------------------------------------------------------------------------
// Accuracy contract (absmax threshold = 2% of max output):
//  * MASK decisions (t_rot>=0, 2<=r<=10, |z|<=4) bit-match the numpy f32
//    reference -> __f*_rn intrinsics (no fp-contract) + rounded sqrtf.
//    Verified absmax==0.0 in R1..R9.
//  * Value path (rotation, weights, fp16 table, sigmoid) is continuous;
//    worst-case ~0.5% relative emission error, 4x under threshold.
struct Prep {
    int   bidx;
    bool  alive;
    float wx0, wx1, wy0, wy1, wz0, wz1;
};

__device__ __forceinline__ Prep prep_point(
    float x, float y, float z, float Om, float tg, float tM, float tinj)
{
    Prep p;
    float t_rot = __fsub_rn(__fsub_rn(tM, tg), tinj);
    float r2 = __fadd_rn(__fadd_rn(__fmul_rn(x, x), __fmul_rn(y, y)),
                         __fmul_rn(z, z));
    float r = sqrtf(r2);

    p.alive = (t_rot >= 0.0f) & (r >= 2.0f) & (r <= 10.0f) &
              (fabsf(z) <= 4.0f);

    // warp-back rotation about z (hardware sin/cos take revolutions)
    float theta = -Om * t_rot;
    float rev = theta * 0.15915494309189535f;
    rev = rev - floorf(rev);
    float s = __builtin_amdgcn_sinf(rev);
    float c = __builtin_amdgcn_cosf(rev);
    float xw = x * c - y * s;
    float yw = x * s + y * c;

    // grid index space: (v + 10) / 20 * 63, clamped into [0, 63)
    float fx = (xw + 10.0f) * 3.15f;
    float fy = (yw + 10.0f) * 3.15f;
    float fz = (z  + 10.0f) * 3.15f;
    fx = fminf(fmaxf(fx, 0.0f), 62.999996f);
    fy = fminf(fmaxf(fy, 0.0f), 62.999996f);
    fz = fminf(fmaxf(fz, 0.0f), 62.999996f);

    int ix0 = (int)fx, iy0 = (int)fy, iz0 = (int)fz;
    p.wx1 = fx - (float)ix0; p.wy1 = fy - (float)iy0; p.wz1 = fz - (float)iz0;
    p.wx0 = 1.0f - p.wx1;    p.wy0 = 1.0f - p.wy1;    p.wz0 = 1.0f - p.wz1;

    int bidx = ix0 * 4096 + iy0 * 64 + iz0;
    p.bidx = p.alive ? bidx : 0;   // dead lanes: broadcast line, no branch
    return p;
}

__device__ __forceinline__ float2 cvt2(unsigned u)
{
    __half2 h = *reinterpret_cast<__half2*>(&u);
    return __half22float2(h);      // 2x v_cvt_f32_f16
}

__device__ __forceinline__ float finish_point(const Prep& p, vu4 cbe)
{
    float2 q00 = cvt2(cbe.x);      // v000, v001
    float2 q01 = cvt2(cbe.y);      // v010, v011
    float2 q10 = cvt2(cbe.z);      // v100, v101
    float2 q11 = cvt2(cbe.w);      // v110, v111

    float c00 = q00.x * p.wz0 + q00.y * p.wz1;
    float c01 = q01.x * p.wz0 + q01.y * p.wz1;
    float c10 = q10.x * p.wz0 + q10.y * p.wz1;
    float c11 = q11.x * p.wz0 + q11.y * p.wz1;
    float c0  = c00 * p.wy0 + c01 * p.wy1;
    float c1  = c10 * p.wy0 + c11 * p.wy1;
    float net = c0 * p.wx0 + c1 * p.wx1;

    float E = __expf(10.0f - net);                 // sigmoid(net - 10)
    float sig = __builtin_amdgcn_rcpf(1.0f + E);
    return p.alive ? sig : 0.0f;
}

#define NTLOAD(ptr)  __builtin_nontemporal_load((const vf4*)(ptr))

// R10 = R6 exact (best measured: bench 91.4us). One-shot, 4 points/thread,
// nt streaming loads (R7 A/B: +5us vs plain — protects the 4MB table in
// L2), one 16B cube gather per point, nt store.
template <bool CUBE>
__global__ __launch_bounds__(256) void grid_predictor_kernel(
    const float* __restrict__ t_frames,
    const float* __restrict__ coords,
    const float* __restrict__ Omega,
    const float* __restrict__ t_geos,
    const float* __restrict__ t_inj,
    const float* __restrict__ t_start,
    const void*  __restrict__ tbl,     // fp16-cube table (CUBE) or raw grid
    float* __restrict__ out)
{
    int i = (blockIdx.x * 256 + threadIdx.x) * 4;

    int t = blockIdx.x >> 9;                       // t uniform per block
    float tM   = __fsub_rn(t_frames[t], t_start[0]);
    float tinj = t_inj[0];

    // Non-temporal streams: zero reuse, keep them out of L2 so the 4MB
    // table stays resident.
    vf4 x4 = NTLOAD(coords + i);
    vf4 y4 = NTLOAD(coords + NELEM + i);
    vf4 z4 = NTLOAD(coords + 2 * NELEM + i);
    vf4 o4 = NTLOAD(Omega + i);
    vf4 g4 = NTLOAD(t_geos + i);

    // phase A: masks + cell addresses + weights for all 4 points
    Prep p0 = prep_point(x4.x, y4.x, z4.x, o4.x, g4.x, tM, tinj);
    Prep p1 = prep_point(x4.y, y4.y, z4.y, o4.y, g4.y, tM, tinj);
    Prep p2 = prep_point(x4.z, y4.z, z4.z, o4.z, g4.z, tM, tinj);
    Prep p3 = prep_point(x4.w, y4.w, z4.w, o4.w, g4.w, tM, tinj);

    vf4 r;
    if (CUBE) {
        // phase B: ONE 16B gather per point, all 4 in flight together
        const vu4* q = (const vu4*)tbl;
        vu4 c0 = q[p0.bidx];
        vu4 c1 = q[p1.bidx];
        vu4 c2 = q[p2.bidx];
        vu4 c3 = q[p3.bidx];
        // phase C: unpack + interpolate + sigmoid + mask
        r.x = finish_point(p0, c0);
        r.y = finish_point(p1, c1);
        r.z = finish_point(p2, c2);
        r.w = finish_point(p3, c3);
    } else {
        // fallback: raw f32 grid, 8 scalar gathers per point
        const float* g = (const float*)tbl;
        #pragma unroll
        for (int k = 0; k < 4; ++k) {
            const Prep& p = k == 0 ? p0 : k == 1 ? p1 : k == 2 ? p2 : p3;
            const float* h = g + p.bidx;
            float c00 = h[0]    * p.wz0 + h[1]    * p.wz1;
            float c01 = h[64]   * p.wz0 + h[65]   * p.wz1;
            float c10 = h[4096] * p.wz0 + h[4097] * p.wz1;
            float c11 = h[4160] * p.wz0 + h[4161] * p.wz1;
            float c0  = c00 * p.wy0 + c01 * p.wy1;
            float c1  = c10 * p.wy0 + c11 * p.wy1;
            float net = c0 * p.wx0 + c1 * p.wx1;
            float E = __expf(10.0f - net);
            float v = __builtin_amdgcn_rcpf(1.0f + E);
            v = p.alive ? v : 0.0f;
            if (k == 0) r.x = v; else if (k == 1) r.y = v;
            else if (k == 2) r.z = v; else r.w = v;
        }
    }

    __builtin_nontemporal_store(r, (vf4*)(out + i));
}

extern "C" void kernel_launch(void* const* d_in, const int* in_sizes, int n_in,
                              void* d_out, int out_size, void* d_ws, size_t ws_size,
                              hipStream_t stream) {
    const float* t_frames = (const float*)d_in[0];
    const float* coords   = (const float*)d_in[1];
    const float* Omega    = (const float*)d_in[2];
    const float* t_geos   = (const float*)d_in[3];
    const float* t_inj    = (const float*)d_in[4];
    const float* t_start  = (const float*)d_in[5];
    const float* grid     = (const float*)d_in[6];
    float* out = (float*)d_out;

    const int threads = 256;
    const int blocks = NELEM / 4 / threads;        // 16384

    if (ws_size >= QBYTES) {
        vu4* q = (vu4*)d_ws;
        build_cube<<<NQ / 256, 256, 0, stream>>>(grid, q);
        grid_predictor_kernel<true><<<blocks, threads, 0, stream>>>(
            t_frames, coords, Omega, t_geos, t_inj, t_start, q, out);
    } else {
        grid_predictor_kernel<false><<<blocks, threads, 0, stream>>>(
            t_frames, coords, Omega, t_geos, t_inj, t_start, grid, out);
    }
}

// Round 11
// 90.865 us; speedup vs baseline: 1.5286x; 1.0087x over previous
//
#include <hip/hip_runtime.h>
#include <hip/hip_fp16.h>
#include <math.h>

// Problem geometry (fixed by setup_inputs)
#define NT    32
#define NA    64
#define NB    64
#define NGEO  128
#define NELEM (NT * NA * NB * NGEO)   // 16777216 = 2^24
#define GR    64
#define NQ    (GR * GR * GR)          // 262144 cells
#define QBYTES ((size_t)NQ * 16)      // 4 MiB packed fp16-cube table

// clang ext-vector types (HIP_vector_type is rejected by the nontemporal
// builtins; vf2 arithmetic lowers to v_pk_*_f32 on gfx950).
typedef float        vf4 __attribute__((ext_vector_type(4)));
typedef float        vf2 __attribute__((ext_vector_type(2)));
typedef unsigned int vu4 __attribute__((ext_vector_type(4)));

// ---------------------------------------------------------------------------
// Pre-pass: pack each cell's full 2x2x2 corner cube as 8 x fp16 in ONE 16B
// record -> one aligned dwordx4 gather per point. fp16 value error <= 2^-11
// relative -> <=0.5% emission error, 4x under the 2% threshold.
// rec = { v000,v001 | v010,v011 | v100,v101 | v110,v111 } packed lo/hi.
__global__ __launch_bounds__(256) void build_cube(
    const float* __restrict__ g, vu4* __restrict__ q)
{
    int idx = blockIdx.x * 256 + threadIdx.x;          // 0 .. NQ-1
    int z = idx & 63, y = (idx >> 6) & 63, x = idx >> 12;
    int zc = min(z + 1, 63), yc = min(y + 1, 63), xc = min(x + 1, 63);
    const float* g0 = g + x  * 4096;
    const float* g1 = g + xc * 4096;
    int b00 = y * 64 + z,  b01 = y * 64 + zc;
    int b10 = yc * 64 + z, b11 = yc * 64 + zc;

    auto pack2 = [](float a, float b) -> unsigned {
        unsigned lo = __half_as_ushort(__float2half(a));
        unsigned hi = __half_as_ushort(__float2half(b));
        return lo | (hi << 16);
    };
    vu4 v;
    v.x = pack2(g0[b00], g0[b01]);
    v.y = pack2(g0[b10], g0[b11]);
    v.z = pack2(g1[b00], g1[b01]);
    v.w = pack2(g1[b10], g1[b11]);
    q[idx] = v;
}

// ---------------------------------------------------------------------------
// Accuracy contract (absmax threshold = 2% of max output):
//  * MASK decisions (t_rot>=0, 2<=r<=10, |z|<=4) bit-match the numpy f32
//    reference -> scalar __f*_rn intrinsics (no fp-contract) + rounded
//    sqrtf. Verified absmax==0.0 in R1..R10.
//  * Value path (rotation, weights, fp16 table, sigmoid) is continuous;
//    packed-f32 (v_pk_*) arithmetic is IEEE-identical per lane-half; fma
//    contraction allowed here. Worst-case ~0.5% relative emission error.
//
// R11: value path packed PAIRWISE across points (v_pk_fma_f32 etc.) to cut
// VALU issue ~35%; memory structure byte-identical to R6/R10 best.
struct Prep2 {
    int  bidx0, bidx1;
    bool alive0, alive1;
    vf2  wx0, wx1, wy0, wy1, wz0, wz1;   // packed across the two points
};

__device__ __forceinline__ Prep2 prep_pair(
    vf2 x, vf2 y, vf2 z, vf2 Om, vf2 tg, float tM, float tinj)
{
    Prep2 p;
    // ---- mask chain: scalar, exact (__f*_rn blocks contraction) ----
    float tr0 = __fsub_rn(__fsub_rn(tM, tg.x), tinj);
    float tr1 = __fsub_rn(__fsub_rn(tM, tg.y), tinj);
    float r20 = __fadd_rn(__fadd_rn(__fmul_rn(x.x, x.x), __fmul_rn(y.x, y.x)),
                          __fmul_rn(z.x, z.x));
    float r21 = __fadd_rn(__fadd_rn(__fmul_rn(x.y, x.y), __fmul_rn(y.y, y.y)),
                          __fmul_rn(z.y, z.y));
    float r0 = sqrtf(r20), r1 = sqrtf(r21);
    p.alive0 = (tr0 >= 0.0f) & (r0 >= 2.0f) & (r0 <= 10.0f) &
               (fabsf(z.x) <= 4.0f);
    p.alive1 = (tr1 >= 0.0f) & (r1 >= 2.0f) & (r1 <= 10.0f) &
               (fabsf(z.y) <= 4.0f);

    // ---- transcendentals: scalar (not packable) ----
    float th0 = -Om.x * tr0, th1 = -Om.y * tr1;
    float rv0 = th0 * 0.15915494309189535f;
    float rv1 = th1 * 0.15915494309189535f;
    rv0 = rv0 - floorf(rv0);
    rv1 = rv1 - floorf(rv1);
    vf2 s = { __builtin_amdgcn_sinf(rv0), __builtin_amdgcn_sinf(rv1) };
    vf2 c = { __builtin_amdgcn_cosf(rv0), __builtin_amdgcn_cosf(rv1) };

    // ---- packed rotation (v_pk_mul / v_pk_fma) ----
    vf2 xw = x * c - y * s;
    vf2 yw = x * s + y * c;

    // ---- packed index transform + clamp: f = v*3.15 + 31.5 in [0,63) ----
    const vf2 K  = (vf2)3.15f, B = (vf2)31.5f;
    const vf2 LO = (vf2)0.0f,  HI = (vf2)62.999996f;
    vf2 fx = __builtin_elementwise_min(
                 __builtin_elementwise_max(xw * K + B, LO), HI);
    vf2 fy = __builtin_elementwise_min(
                 __builtin_elementwise_max(yw * K + B, LO), HI);
    vf2 fz = __builtin_elementwise_min(
                 __builtin_elementwise_max(z  * K + B, LO), HI);

    int ix0 = (int)fx.x, ix1 = (int)fx.y;
    int iy0 = (int)fy.x, iy1 = (int)fy.y;
    int iz0 = (int)fz.x, iz1 = (int)fz.y;

    // ---- packed weights ----
    p.wx1 = fx - (vf2){(float)ix0, (float)ix1};
    p.wy1 = fy - (vf2){(float)iy0, (float)iy1};
    p.wz1 = fz - (vf2){(float)iz0, (float)iz1};
    p.wx0 = (vf2)1.0f - p.wx1;
    p.wy0 = (vf2)1.0f - p.wy1;
    p.wz0 = (vf2)1.0f - p.wz1;

    int b0 = ix0 * 4096 + iy0 * 64 + iz0;
    int b1 = ix1 * 4096 + iy1 * 64 + iz1;
    p.bidx0 = p.alive0 ? b0 : 0;   // dead lanes: broadcast line, no branch
    p.bidx1 = p.alive1 ? b1 : 0;
    return p;
}

__device__ __forceinline__ vf2 cvt2(unsigned u)
{
    __half2 h = __builtin_bit_cast(__half2, u);
    float2 f = __half22float2(h);          // 2x v_cvt_f32_f16
    return (vf2){f.x, f.y};
}

// Finish two points with packed trilinear lerps (pairs formed ACROSS the
// two points; regrouping is free — vf2 components are separate VGPRs).
__device__ __forceinline__ vf2 finish_pair(const Prep2& p, vu4 ca, vu4 cb)
{
    vf2 a0 = cvt2(ca.x), a1 = cvt2(ca.y), a2 = cvt2(ca.z), a3 = cvt2(ca.w);
    vf2 b0 = cvt2(cb.x), b1 = cvt2(cb.y), b2 = cvt2(cb.z), b3 = cvt2(cb.w);

    // cross-point corner pairs: vNNN = (point0.vNNN, point1.vNNN)
    vf2 v000 = {a0.x, b0.x}, v001 = {a0.y, b0.y};
    vf2 v010 = {a1.x, b1.x}, v011 = {a1.y, b1.y};
    vf2 v100 = {a2.x, b2.x}, v101 = {a2.y, b2.y};
    vf2 v110 = {a3.x, b3.x}, v111 = {a3.y, b3.y};

    vf2 c00 = v000 * p.wz0 + v001 * p.wz1;     // all v_pk_mul/v_pk_fma
    vf2 c01 = v010 * p.wz0 + v011 * p.wz1;
    vf2 c10 = v100 * p.wz0 + v101 * p.wz1;
    vf2 c11 = v110 * p.wz0 + v111 * p.wz1;
    vf2 c0  = c00 * p.wy0 + c01 * p.wy1;
    vf2 c1  = c10 * p.wy0 + c11 * p.wy1;
    vf2 net = c0 * p.wx0 + c1 * p.wx1;

    // sigmoid(net - 10): scalar trans
    float E0 = __expf(10.0f - net.x);
    float E1 = __expf(10.0f - net.y);
    float s0 = __builtin_amdgcn_rcpf(1.0f + E0);
    float s1 = __builtin_amdgcn_rcpf(1.0f + E1);
    return (vf2){ p.alive0 ? s0 : 0.0f, p.alive1 ? s1 : 0.0f };
}

#define NTLOAD(ptr)  __builtin_nontemporal_load((const vf4*)(ptr))

__global__ __launch_bounds__(256) void grid_predictor_pk(
    const float* __restrict__ t_frames,
    const float* __restrict__ coords,
    const float* __restrict__ Omega,
    const float* __restrict__ t_geos,
    const float* __restrict__ t_inj,
    const float* __restrict__ t_start,
    const vu4*  __restrict__ q,
    float* __restrict__ out)
{
    int i = (blockIdx.x * 256 + threadIdx.x) * 4;

    int t = blockIdx.x >> 9;                       // t uniform per block
    float tM   = __fsub_rn(t_frames[t], t_start[0]);
    float tinj = t_inj[0];

    // Non-temporal streams (R7 A/B: +5us vs plain — protects the 4MB
    // table's L2 residency).
    vf4 x4 = NTLOAD(coords + i);
    vf4 y4 = NTLOAD(coords + NELEM + i);
    vf4 z4 = NTLOAD(coords + 2 * NELEM + i);
    vf4 o4 = NTLOAD(Omega + i);
    vf4 g4 = NTLOAD(t_geos + i);

    // phase A: masks + addresses + weights, two packed pairs
    Prep2 pA = prep_pair((vf2){x4.x, x4.y}, (vf2){y4.x, y4.y},
                         (vf2){z4.x, z4.y}, (vf2){o4.x, o4.y},
                         (vf2){g4.x, g4.y}, tM, tinj);
    Prep2 pB = prep_pair((vf2){x4.z, x4.w}, (vf2){y4.z, y4.w},
                         (vf2){z4.z, z4.w}, (vf2){o4.z, o4.w},
                         (vf2){g4.z, g4.w}, tM, tinj);

    // phase B: ONE 16B gather per point, all 4 in flight together
    vu4 c0 = q[pA.bidx0];
    vu4 c1 = q[pA.bidx1];
    vu4 c2 = q[pB.bidx0];
    vu4 c3 = q[pB.bidx1];

    // phase C: packed unpack + trilinear + sigmoid + mask
    vf2 rA = finish_pair(pA, c0, c1);
    vf2 rB = finish_pair(pB, c2, c3);

    vf4 r = { rA.x, rA.y, rB.x, rB.y };
    __builtin_nontemporal_store(r, (vf4*)(out + i));
}

// Fallback (no workspace): scalar 4-pt direct-grid kernel, f32 gathers.
__global__ __launch_bounds__(256) void grid_predictor4_raw(
    const float* __restrict__ t_frames,
    const float* __restrict__ coords,
    const float* __restrict__ Omega,
    const float* __restrict__ t_geos,
    const float* __restrict__ t_inj,
    const float* __restrict__ t_start,
    const float* __restrict__ g,
    float* __restrict__ out)
{
    int i = (blockIdx.x * 256 + threadIdx.x) * 4;
    int t = blockIdx.x >> 9;
    float tM   = __fsub_rn(t_frames[t], t_start[0]);
    float tinj = t_inj[0];

    vf4 x4 = NTLOAD(coords + i);
    vf4 y4 = NTLOAD(coords + NELEM + i);
    vf4 z4 = NTLOAD(coords + 2 * NELEM + i);
    vf4 o4 = NTLOAD(Omega + i);
    vf4 g4 = NTLOAD(t_geos + i);

    vf4 r;
    #pragma unroll
    for (int k = 0; k < 4; ++k) {
        float x = x4[k], y = y4[k], z = z4[k], Om = o4[k], tg = g4[k];
        float t_rot = __fsub_rn(__fsub_rn(tM, tg), tinj);
        float r2 = __fadd_rn(__fadd_rn(__fmul_rn(x, x), __fmul_rn(y, y)),
                             __fmul_rn(z, z));
        float rr = sqrtf(r2);
        bool alive = (t_rot >= 0.0f) & (rr >= 2.0f) & (rr <= 10.0f) &
                     (fabsf(z) <= 4.0f);
        float theta = -Om * t_rot;
        float rev = theta * 0.15915494309189535f;
        rev = rev - floorf(rev);
        float s = __builtin_amdgcn_sinf(rev);
        float c = __builtin_amdgcn_cosf(rev);
        float xw = x * c - y * s;
        float yw = x * s + y * c;
        float fx = fminf(fmaxf(xw * 3.15f + 31.5f, 0.0f), 62.999996f);
        float fy = fminf(fmaxf(yw * 3.15f + 31.5f, 0.0f), 62.999996f);
        float fz = fminf(fmaxf(z  * 3.15f + 31.5f, 0.0f), 62.999996f);
        int ix0 = (int)fx, iy0 = (int)fy, iz0 = (int)fz;
        float wx1 = fx - (float)ix0, wy1 = fy - (float)iy0,
              wz1 = fz - (float)iz0;
        float wx0 = 1.0f - wx1, wy0 = 1.0f - wy1, wz0 = 1.0f - wz1;
        int bidx = alive ? (ix0 * 4096 + iy0 * 64 + iz0) : 0;
        const float* h = g + bidx;
        float c00 = h[0]    * wz0 + h[1]    * wz1;
        float c01 = h[64]   * wz0 + h[65]   * wz1;
        float c10 = h[4096] * wz0 + h[4097] * wz1;
        float c11 = h[4160] * wz0 + h[4161] * wz1;
        float c0  = c00 * wy0 + c01 * wy1;
        float c1  = c10 * wy0 + c11 * wy1;
        float net = c0 * wx0 + c1 * wx1;
        float E = __expf(10.0f - net);
        float v = __builtin_amdgcn_rcpf(1.0f + E);
        r[k] = alive ? v : 0.0f;
    }
    __builtin_nontemporal_store(r, (vf4*)(out + i));
}

extern "C" void kernel_launch(void* const* d_in, const int* in_sizes, int n_in,
                              void* d_out, int out_size, void* d_ws, size_t ws_size,
                              hipStream_t stream) {
    const float* t_frames = (const float*)d_in[0];
    const float* coords   = (const float*)d_in[1];
    const float* Omega    = (const float*)d_in[2];
    const float* t_geos   = (const float*)d_in[3];
    const float* t_inj    = (const float*)d_in[4];
    const float* t_start  = (const float*)d_in[5];
    const float* grid     = (const float*)d_in[6];
    float* out = (float*)d_out;

    const int threads = 256;
    const int blocks = NELEM / 4 / threads;        // 16384

    if (ws_size >= QBYTES) {
        vu4* q = (vu4*)d_ws;
        build_cube<<<NQ / 256, 256, 0, stream>>>(grid, q);
        grid_predictor_pk<<<blocks, threads, 0, stream>>>(
            t_frames, coords, Omega, t_geos, t_inj, t_start, q, out);
    } else {
        grid_predictor4_raw<<<blocks, threads, 0, stream>>>(
            t_frames, coords, Omega, t_geos, t_inj, t_start, grid, out);
    }
}